// Round 8
// baseline (563.832 us; speedup 1.0000x reference)
//
#include <hip/hip_runtime.h>
#include <hip/hip_bf16.h>

// Problem constants
#define Dsz 768
#define Psz 256
#define Hsz 12
#define DHsz 64
#define DFFsz 3072
#define Msz 512           // rows of all activation matrices (2*P)
#define EPS_LN 1e-5f
#define EPS_TRIP 1e-6f
#define NBLK 256

typedef unsigned short u16;
typedef __attribute__((ext_vector_type(8))) short bf16x8;
typedef __attribute__((ext_vector_type(4))) float f32x4;

__device__ __forceinline__ u16 f2bf(float f) {
    __hip_bfloat16 h = __float2bfloat16(f);
    u16 u; __builtin_memcpy(&u, &h, 2); return u;
}

// ---------- device-scope grid barrier (one-shot counters, zeroed by host memset) ----------
__device__ __forceinline__ void gridbar(unsigned* c) {
    __syncthreads();
    if (threadIdx.x == 0) {
        __threadfence();   // release: prior writes visible device-wide
        __hip_atomic_fetch_add(c, 1u, __ATOMIC_RELEASE, __HIP_MEMORY_SCOPE_AGENT);
        while (__hip_atomic_load(c, __ATOMIC_ACQUIRE, __HIP_MEMORY_SCOPE_AGENT) < NBLK) {
            __builtin_amdgcn_s_sleep(1);
        }
        __threadfence();   // acquire
    }
    __syncthreads();
}

// ---------- MFMA bf16 GEMM tile (64x64 out, 4 waves 2x2, K-loop) ----------
// Fragment layouts (m89-verified family):
//   a: A[row0 + (l&15)][k + (l>>4)*8 + e]
//   b: WT[col0 + (l&15)][k + (l>>4)*8 + e]   (WT[N,K] = W^T)
//   d: C[row0 + (l>>4)*4 + e][col0 + (l&15)]
__device__ void mfma_tile(
    const u16* __restrict__ A, int lda,
    const u16* __restrict__ WT, int ldw,
    const float* __restrict__ bias,
    float* __restrict__ Cf, u16* __restrict__ Cb, int ldc,
    int Kloop, int relu, int bx, int by)
{
    int tid = threadIdx.x;
    int lane = tid & 63, wave = tid >> 6;
    int wr = wave >> 1, wc = wave & 1;
    int row0 = by*64 + wr*32, col0 = bx*64 + wc*32;
    int r = lane & 15, kg = lane >> 4;
    const u16* Ap0 = A  + (size_t)(row0 + r)      * lda + kg*8;
    const u16* Ap1 = A  + (size_t)(row0 + 16 + r) * lda + kg*8;
    const u16* Bp0 = WT + (size_t)(col0 + r)      * ldw + kg*8;
    const u16* Bp1 = WT + (size_t)(col0 + 16 + r) * ldw + kg*8;
    f32x4 acc00 = {0.f,0.f,0.f,0.f}, acc01 = {0.f,0.f,0.f,0.f};
    f32x4 acc10 = {0.f,0.f,0.f,0.f}, acc11 = {0.f,0.f,0.f,0.f};
    for (int k = 0; k < Kloop; k += 64) {
        bf16x8 a0 = *(const bf16x8*)(Ap0 + k);
        bf16x8 a1 = *(const bf16x8*)(Ap1 + k);
        bf16x8 b0 = *(const bf16x8*)(Bp0 + k);
        bf16x8 b1 = *(const bf16x8*)(Bp1 + k);
        bf16x8 a2 = *(const bf16x8*)(Ap0 + k + 32);
        bf16x8 a3 = *(const bf16x8*)(Ap1 + k + 32);
        bf16x8 b2 = *(const bf16x8*)(Bp0 + k + 32);
        bf16x8 b3 = *(const bf16x8*)(Bp1 + k + 32);
        acc00 = __builtin_amdgcn_mfma_f32_16x16x32_bf16(a0, b0, acc00, 0, 0, 0);
        acc01 = __builtin_amdgcn_mfma_f32_16x16x32_bf16(a0, b1, acc01, 0, 0, 0);
        acc10 = __builtin_amdgcn_mfma_f32_16x16x32_bf16(a1, b0, acc10, 0, 0, 0);
        acc11 = __builtin_amdgcn_mfma_f32_16x16x32_bf16(a1, b1, acc11, 0, 0, 0);
        acc00 = __builtin_amdgcn_mfma_f32_16x16x32_bf16(a2, b2, acc00, 0, 0, 0);
        acc01 = __builtin_amdgcn_mfma_f32_16x16x32_bf16(a2, b3, acc01, 0, 0, 0);
        acc10 = __builtin_amdgcn_mfma_f32_16x16x32_bf16(a3, b2, acc10, 0, 0, 0);
        acc11 = __builtin_amdgcn_mfma_f32_16x16x32_bf16(a3, b3, acc11, 0, 0, 0);
    }
    float b0s = bias ? bias[col0 + r]      : 0.f;
    float b1s = bias ? bias[col0 + 16 + r] : 0.f;
    #pragma unroll
    for (int e = 0; e < 4; ++e) {
        int rr0 = row0 + kg*4 + e;
        int rr1 = rr0 + 16;
        float v00 = acc00[e] + b0s, v01 = acc01[e] + b1s;
        float v10 = acc10[e] + b0s, v11 = acc11[e] + b1s;
        if (relu) {
            v00 = fmaxf(v00, 0.f); v01 = fmaxf(v01, 0.f);
            v10 = fmaxf(v10, 0.f); v11 = fmaxf(v11, 0.f);
        }
        if (Cf) {
            Cf[(size_t)rr0*ldc + col0 + r]      = v00;
            Cf[(size_t)rr0*ldc + col0 + 16 + r] = v01;
            Cf[(size_t)rr1*ldc + col0 + r]      = v10;
            Cf[(size_t)rr1*ldc + col0 + 16 + r] = v11;
        }
        if (Cb) {
            Cb[(size_t)rr0*ldc + col0 + r]      = f2bf(v00);
            Cb[(size_t)rr0*ldc + col0 + 16 + r] = f2bf(v01);
            Cb[(size_t)rr1*ldc + col0 + r]      = f2bf(v10);
            Cb[(size_t)rr1*ldc + col0 + 16 + r] = f2bf(v11);
        }
    }
}

// ---------- block-wide sum reduce (256 thr), sb is shared float[4+] ----------
__device__ __forceinline__ float blk_sum(float s, float* sb) {
    #pragma unroll
    for (int off = 32; off; off >>= 1) s += __shfl_xor(s, off);
    if ((threadIdx.x & 63) == 0) sb[threadIdx.x >> 6] = s;
    __syncthreads();
    float tot = sb[0] + sb[1] + sb[2] + sb[3];
    __syncthreads();
    return tot;
}

struct FusedArgs {
    const float* sent; const int* sidx; const int* sspan; const int* pspan; const int* nspan;
    const float* Wq; const float* bq; const float* Wk; const float* bk;
    const float* Wv; const float* bv; const float* Wo; const float* bo;
    const float* ln1g; const float* ln1b; const float* ln2g; const float* ln2b;
    const float* W1; const float* b1; const float* W2; const float* b2;
    // cvt work list
    const float* csrc[6]; u16* cdst[6]; int cK[6], cN[6], ct0[7];
    // workspace
    float *mem, *qin, *hbuf, *p0, *p1, *qh, *kh, *vh, *rowsq;
    u16 *memb, *qinb, *obufb, *hbufb, *f1b, *WqT, *WkT, *WvT, *WoT, *W1T, *W2T;
    unsigned* bar;
    float* out;
};

__global__ __launch_bounds__(256, 2) void fused_kernel(FusedArgs a)
{
    __shared__ float tile[64][65];   // cvt transpose staging (16.6 KB)
    __shared__ float sb[4];
    int b   = blockIdx.x;
    int tid = threadIdx.x;
    int wave = tid >> 6, lane = tid & 63;

    // ---- Stage 1: pool (pair b) ----
    {
        int p = b;
        int bb = a.sidx[p];
        const float* base = a.sent + (size_t)bb * 512 * Dsz;
        int ss = a.sspan[2*p], se = a.sspan[2*p+1];
        int ps = a.pspan[2*p], pe = a.pspan[2*p+1];
        int ns = a.nspan[2*p], ne = a.nspan[2*p+1];
        float is  = 1.0f / (float)(se - ss);
        float ip  = 1.0f / (float)(pe - ps);
        float in_ = 1.0f / (float)(ne - ns);
        for (int d = tid; d < Dsz; d += 256) {
            float cls = base[d];
            float as = 0.f, ap = 0.f, an = 0.f;
            for (int s = ss; s < se; ++s) as += base[(size_t)s*Dsz + d];
            for (int s = ps; s < pe; ++s) ap += base[(size_t)s*Dsz + d];
            for (int s = ns; s < ne; ++s) an += base[(size_t)s*Dsz + d];
            as *= is; ap *= ip; an *= in_;
            a.mem[(size_t)(2*p+0)*Dsz + d] = cls;
            a.mem[(size_t)(2*p+1)*Dsz + d] = as;
            a.qin[(size_t)(0*Psz + p)*Dsz + d] = ap;
            a.qin[(size_t)(1*Psz + p)*Dsz + d] = an;
            a.memb[(size_t)(2*p+0)*Dsz + d] = f2bf(cls);
            a.memb[(size_t)(2*p+1)*Dsz + d] = f2bf(as);
            a.qinb[(size_t)(0*Psz + p)*Dsz + d] = f2bf(ap);
            a.qinb[(size_t)(1*Psz + p)*Dsz + d] = f2bf(an);
        }
    }
    // ---- Stage 2: weight convert+transpose, 1728 tiles ----
    for (int t = b; t < 1728; t += NBLK) {
        __syncthreads();             // tile[] reuse guard
        int w = 0;
        while (t >= a.ct0[w+1]) ++w;
        int local = t - a.ct0[w];
        int K = a.cK[w], N = a.cN[w];
        int ntN = N >> 6;
        int tk = local / ntN, tn = local - tk * ntN;
        int k0 = tk << 6, n0 = tn << 6;
        const float* src = a.csrc[w];
        u16* dst = a.cdst[w];
        int rr = tid >> 2, q = tid & 3;
        #pragma unroll
        for (int j = 0; j < 4; ++j) {
            int c4 = q + j*4;
            float4 v = *(const float4*)(src + (size_t)(k0 + rr)*N + n0 + c4*4);
            tile[rr][c4*4+0] = v.x; tile[rr][c4*4+1] = v.y;
            tile[rr][c4*4+2] = v.z; tile[rr][c4*4+3] = v.w;
        }
        __syncthreads();
        #pragma unroll
        for (int j = 0; j < 4; ++j) {
            int kc4 = q + j*4;
            ushort4 o;
            o.x = f2bf(tile[kc4*4+0][rr]);
            o.y = f2bf(tile[kc4*4+1][rr]);
            o.z = f2bf(tile[kc4*4+2][rr]);
            o.w = f2bf(tile[kc4*4+3][rr]);
            *(ushort4*)(dst + (size_t)(n0 + rr)*K + k0 + kc4*4) = o;
        }
    }
    gridbar(a.bar + 0);

    // ---- Stage 3: QKV projections (288 tiles: 96 each for K,V,Q) ----
    for (int t = b; t < 288; t += NBLK) {
        int j = t / 96, u = t % 96;
        int bx = u % 12, by = u / 12;
        const u16* A  = (j == 2) ? a.qinb : a.memb;
        const u16* WT = (j == 0) ? a.WkT : (j == 1) ? a.WvT : a.WqT;
        const float* bias = (j == 0) ? a.bk : (j == 1) ? a.bv : a.bq;
        float* C = (j == 0) ? a.kh : (j == 1) ? a.vh : a.qh;
        mfma_tile(A, Dsz, WT, Dsz, bias, C, nullptr, Dsz, Dsz, 0, bx, by);
    }
    gridbar(a.bar + 1);

    // ---- Stage 4: attention (2 rows/block; 2 waves per row, 6 heads each) ----
    {
        int rrow = 2*b + (wave >> 1);
        int p = rrow & (Psz - 1);
        int hseg = (wave & 1) * 6;
        const float* q  = a.qh + (size_t)rrow * Dsz;
        const float* k0 = a.kh + (size_t)(2*p) * Dsz;
        const float* k1 = k0 + Dsz;
        const float* v0 = a.vh + (size_t)(2*p) * Dsz;
        const float* v1 = v0 + Dsz;
        u16* o = a.obufb + (size_t)rrow * Dsz;
        #pragma unroll
        for (int hh = 0; hh < 6; ++hh) {
            int idx = (hseg + hh) * DHsz + lane;
            float qv = q[idx];
            float s0 = qv * k0[idx];
            float s1 = qv * k1[idx];
            #pragma unroll
            for (int off = 32; off; off >>= 1) {
                s0 += __shfl_xor(s0, off);
                s1 += __shfl_xor(s1, off);
            }
            s0 *= 0.125f;  s1 *= 0.125f;   // 1/sqrt(64)
            float m = fmaxf(s0, s1);
            float e0 = expf(s0 - m), e1 = expf(s1 - m);
            float inv = 1.f / (e0 + e1);
            o[idx] = f2bf((e0 * inv) * v0[idx] + (e1 * inv) * v1[idx]);
        }
    }
    gridbar(a.bar + 2);

    // ---- Stage 5: Wo projection, split-K=2 (192 work items), partials p0/p1 ----
    for (int t = b; t < 192; t += NBLK) {
        int s = t / 96, u = t % 96;
        int bx = u % 12, by = u / 12;
        mfma_tile(a.obufb + (size_t)s * 384, Dsz, a.WoT + (size_t)s * 384, Dsz,
                  (s == 0) ? a.bo : nullptr,
                  (s == 0) ? a.p0 : a.p1, nullptr, Dsz, 384, 0, bx, by);
    }
    gridbar(a.bar + 3);

    // ---- Stage 6: h = LN1(qin + p0 + p1), f32 + bf16 (2 rows/block) ----
    for (int i = 0; i < 2; ++i) {
        int rrow = 2*b + i;
        float v[3]; float s = 0.f;
        #pragma unroll
        for (int j = 0; j < 3; ++j) {
            int d = tid + j * 256;
            size_t ix = (size_t)rrow*Dsz + d;
            float acc = a.qin[ix] + a.p0[ix] + a.p1[ix];
            v[j] = acc; s += acc;
        }
        float mean = blk_sum(s, sb) * (1.0f / Dsz);
        float sv = 0.f;
        #pragma unroll
        for (int j = 0; j < 3; ++j) { float d0 = v[j] - mean; sv += d0 * d0; }
        float var = blk_sum(sv, sb) * (1.0f / Dsz);
        float rstd = 1.0f / sqrtf(var + EPS_LN);
        #pragma unroll
        for (int j = 0; j < 3; ++j) {
            int d = tid + j * 256;
            float o = (v[j] - mean) * rstd * a.ln1g[d] + a.ln1b[d];
            a.hbuf[(size_t)rrow*Dsz + d] = o;
            a.hbufb[(size_t)rrow*Dsz + d] = f2bf(o);
        }
        __syncthreads();
    }
    gridbar(a.bar + 4);

    // ---- Stage 7: f1 = relu(h @ W1 + b1), bf16 (384 tiles) ----
    for (int t = b; t < 384; t += NBLK) {
        int bx = t % 48, by = t / 48;
        mfma_tile(a.hbufb, Dsz, a.W1T, Dsz, a.b1,
                  nullptr, a.f1b, DFFsz, Dsz, 1, bx, by);
    }
    gridbar(a.bar + 5);

    // ---- Stage 8: f2 = f1 @ W2 + b2, split-K=2 (192 items), partials p0/p1 ----
    for (int t = b; t < 192; t += NBLK) {
        int s = t / 96, u = t % 96;
        int bx = u % 12, by = u / 12;
        mfma_tile(a.f1b + (size_t)s * 1536, DFFsz, a.W2T + (size_t)s * 1536, DFFsz,
                  (s == 0) ? a.b2 : nullptr,
                  (s == 0) ? a.p0 : a.p1, nullptr, Dsz, 1536, 0, bx, by);
    }
    gridbar(a.bar + 6);

    // ---- Stage 9: out = LN2(h + p0 + p1) and per-row loss sumsq ----
    for (int i = 0; i < 2; ++i) {
        int rrow = 2*b + i;
        int p = rrow & (Psz - 1);
        const float* se = a.mem + (size_t)(2*p+1) * Dsz;
        float v[3]; float s = 0.f;
        #pragma unroll
        for (int j = 0; j < 3; ++j) {
            int d = tid + j * 256;
            size_t ix = (size_t)rrow*Dsz + d;
            float acc = a.hbuf[ix] + a.p0[ix] + a.p1[ix];
            v[j] = acc; s += acc;
        }
        float mean = blk_sum(s, sb) * (1.0f / Dsz);
        float sv = 0.f;
        #pragma unroll
        for (int j = 0; j < 3; ++j) { float d0 = v[j] - mean; sv += d0 * d0; }
        float var = blk_sum(sv, sb) * (1.0f / Dsz);
        float rstd = 1.0f / sqrtf(var + EPS_LN);
        float dsq = 0.f;
        #pragma unroll
        for (int j = 0; j < 3; ++j) {
            int d = tid + j * 256;
            float o = (v[j] - mean) * rstd * a.ln2g[d] + a.ln2b[d];
            float diff = se[d] - o + EPS_TRIP;
            dsq += diff * diff;
        }
        float tot = blk_sum(dsq, sb);
        if (tid == 0) a.rowsq[rrow] = tot;
        __syncthreads();
    }
    gridbar(a.bar + 7);

    // ---- Stage 10: final triplet loss (block 0 only, direct write) ----
    if (b == 0) {
        float dp = sqrtf(a.rowsq[tid]);
        float dn = sqrtf(a.rowsq[Psz + tid]);
        float l = fmaxf(dp - dn + 1.0f, 0.f);
        float tot = blk_sum(l, sb);
        if (tid == 0) a.out[0] = tot * (1.0f / Psz);
    }
}

// ---------------- Launch ----------------
extern "C" void kernel_launch(void* const* d_in, const int* in_sizes, int n_in,
                              void* d_out, int out_size, void* d_ws, size_t ws_size,
                              hipStream_t stream) {
    FusedArgs a;
    a.sent  = (const float*)d_in[0];
    a.sidx  = (const int*)d_in[1];
    a.sspan = (const int*)d_in[2];
    a.pspan = (const int*)d_in[3];
    a.nspan = (const int*)d_in[4];
    a.Wq = (const float*)d_in[5];  a.bq = (const float*)d_in[6];
    a.Wk = (const float*)d_in[7];  a.bk = (const float*)d_in[8];
    a.Wv = (const float*)d_in[9];  a.bv = (const float*)d_in[10];
    a.Wo = (const float*)d_in[11]; a.bo = (const float*)d_in[12];
    a.ln1g = (const float*)d_in[13]; a.ln1b = (const float*)d_in[14];
    a.ln2g = (const float*)d_in[15]; a.ln2b = (const float*)d_in[16];
    a.W1 = (const float*)d_in[17]; a.b1 = (const float*)d_in[18];
    a.W2 = (const float*)d_in[19]; a.b2 = (const float*)d_in[20];
    a.out = (float*)d_out;

    // Workspace (floats); F = 512*768 = 393216 (1.5 MB). ws_size ≈ 268 MB.
    const size_t F = (size_t)Msz * Dsz;
    float* ws = (float*)d_ws;
    a.mem   = ws + 0*F;
    a.qin   = ws + 1*F;
    a.hbuf  = ws + 2*F;
    a.qh = a.p0 = ws + 3*F;    // overlap: qh last read stage 4, p0 first write stage 5
    a.kh = a.p1 = ws + 4*F;    // overlap: kh last read stage 4, p1 first write stage 5
    a.vh    = ws + 5*F;
    a.rowsq = ws + 6*F;        // 512 floats
    a.bar   = (unsigned*)(ws + 6*F + 768);   // 8 counters
    a.memb  = (u16*)(ws + 7*F);
    a.qinb  = (u16*)(ws + 8*F);
    a.obufb = (u16*)(ws + 9*F);
    a.hbufb = (u16*)(ws + 10*F);
    a.f1b   = (u16*)(ws + 11*F);             // [512,3072] bf16 = 2F floats
    a.WqT   = (u16*)(ws + 13*F);
    a.WkT   = (u16*)(ws + 14*F);
    a.WvT   = (u16*)(ws + 15*F);
    a.WoT   = (u16*)(ws + 16*F);
    a.W1T   = (u16*)(ws + 17*F);             // [3072,768] bf16 = 3F floats
    a.W2T   = (u16*)(ws + 20*F);             // [768,3072] bf16 = 3F floats -> end 23F ≈ 36 MB

    // cvt work list
    a.csrc[0]=a.Wq; a.csrc[1]=a.Wk; a.csrc[2]=a.Wv; a.csrc[3]=a.Wo; a.csrc[4]=a.W1; a.csrc[5]=a.W2;
    a.cdst[0]=a.WqT; a.cdst[1]=a.WkT; a.cdst[2]=a.WvT; a.cdst[3]=a.WoT; a.cdst[4]=a.W1T; a.cdst[5]=a.W2T;
    a.cK[0]=Dsz; a.cK[1]=Dsz; a.cK[2]=Dsz; a.cK[3]=Dsz; a.cK[4]=Dsz;  a.cK[5]=DFFsz;
    a.cN[0]=Dsz; a.cN[1]=Dsz; a.cN[2]=Dsz; a.cN[3]=Dsz; a.cN[4]=DFFsz; a.cN[5]=Dsz;
    int acc_t = 0;
    for (int i = 0; i < 6; ++i) {
        a.ct0[i] = acc_t;
        acc_t += (a.cK[i] >> 6) * (a.cN[i] >> 6);
    }
    a.ct0[6] = acc_t;   // 1728

    // zero the barrier counters (graph-capture-safe async memset)
    hipMemsetAsync((void*)a.bar, 0, 64, stream);

    fused_kernel<<<NBLK, 256, 0, stream>>>(a);
}

// Round 10
// 254.666 us; speedup vs baseline: 2.2140x; 2.2140x over previous
//
#include <hip/hip_runtime.h>
#include <hip/hip_bf16.h>

// Problem constants
#define Dsz 768
#define Psz 256
#define Hsz 12
#define DHsz 64
#define DFFsz 3072
#define Msz 512           // rows of all activation matrices (2*P)
#define EPS_LN 1e-5f
#define EPS_TRIP 1e-6f

typedef unsigned short u16;
typedef __attribute__((ext_vector_type(8))) short bf16x8;
typedef __attribute__((ext_vector_type(4))) float f32x4;

__device__ __forceinline__ u16 f2bf(float f) {
    __hip_bfloat16 h = __float2bfloat16(f);
    u16 u; __builtin_memcpy(&u, &h, 2); return u;
}

// ---------- block-wide sum reduce (256 thr) ----------
__device__ __forceinline__ float blk_sum(float s, float* sb) {
    #pragma unroll
    for (int off = 32; off; off >>= 1) s += __shfl_xor(s, off);
    if ((threadIdx.x & 63) == 0) sb[threadIdx.x >> 6] = s;
    __syncthreads();
    float tot = sb[0] + sb[1] + sb[2] + sb[3];
    __syncthreads();
    return tot;
}

// ---------------- Fused pool + weight-cvt kernel ----------------
// blocks [0,256): pool pair b. blocks [256, 256+1728): weight cvt tile.
struct PoolCvtArgs {
    const float* sent; const int* sidx; const int* sspan; const int* pspan; const int* nspan;
    float* mem; float* qin; u16* memb; u16* qinb;
    const float* csrc[6]; u16* cdst[6]; int cK[6], cN[6], ct0[7];
};

__global__ __launch_bounds__(256) void pool_cvt_kernel(PoolCvtArgs a)
{
    __shared__ float tile[64][65];
    int bid = blockIdx.x;
    int tid = threadIdx.x;
    if (bid < Psz) {
        // ---- pool ----
        int p = bid;
        int bb = a.sidx[p];
        const float* base = a.sent + (size_t)bb * 512 * Dsz;
        int ss = a.sspan[2*p], se = a.sspan[2*p+1];
        int ps = a.pspan[2*p], pe = a.pspan[2*p+1];
        int ns = a.nspan[2*p], ne = a.nspan[2*p+1];
        float is  = 1.0f / (float)(se - ss);
        float ip  = 1.0f / (float)(pe - ps);
        float in_ = 1.0f / (float)(ne - ns);
        for (int d = tid; d < Dsz; d += 256) {
            float cls = base[d];
            float as = 0.f, ap = 0.f, an = 0.f;
            for (int s = ss; s < se; ++s) as += base[(size_t)s*Dsz + d];
            for (int s = ps; s < pe; ++s) ap += base[(size_t)s*Dsz + d];
            for (int s = ns; s < ne; ++s) an += base[(size_t)s*Dsz + d];
            as *= is; ap *= ip; an *= in_;
            a.mem[(size_t)(2*p+0)*Dsz + d] = cls;
            a.mem[(size_t)(2*p+1)*Dsz + d] = as;
            a.qin[(size_t)(0*Psz + p)*Dsz + d] = ap;
            a.qin[(size_t)(1*Psz + p)*Dsz + d] = an;
            a.memb[(size_t)(2*p+0)*Dsz + d] = f2bf(cls);
            a.memb[(size_t)(2*p+1)*Dsz + d] = f2bf(as);
            a.qinb[(size_t)(0*Psz + p)*Dsz + d] = f2bf(ap);
            a.qinb[(size_t)(1*Psz + p)*Dsz + d] = f2bf(an);
        }
    } else {
        // ---- weight convert + transpose: W[K,N] f32 -> WT[N,K] bf16 ----
        int t = bid - Psz;
        int w = 0;
        while (t >= a.ct0[w+1]) ++w;
        int local = t - a.ct0[w];
        int K = a.cK[w], N = a.cN[w];
        int ntN = N >> 6;
        int tk = local / ntN, tn = local - tk * ntN;
        int k0 = tk << 6, n0 = tn << 6;
        const float* src = a.csrc[w];
        u16* dst = a.cdst[w];
        int rr = tid >> 2, q = tid & 3;
        #pragma unroll
        for (int j = 0; j < 4; ++j) {
            int c4 = q + j*4;
            float4 v = *(const float4*)(src + (size_t)(k0 + rr)*N + n0 + c4*4);
            tile[rr][c4*4+0] = v.x; tile[rr][c4*4+1] = v.y;
            tile[rr][c4*4+2] = v.z; tile[rr][c4*4+3] = v.w;
        }
        __syncthreads();
        #pragma unroll
        for (int j = 0; j < 4; ++j) {
            int kc4 = q + j*4;
            ushort4 o;
            o.x = f2bf(tile[kc4*4+0][rr]);
            o.y = f2bf(tile[kc4*4+1][rr]);
            o.z = f2bf(tile[kc4*4+2][rr]);
            o.w = f2bf(tile[kc4*4+3][rr]);
            *(ushort4*)(dst + (size_t)(n0 + rr)*K + k0 + kc4*4) = o;
        }
    }
}

// ---------------- MFMA bf16 GEMM core (64x64 block tile, 4 waves) ----------------
// Fragment layouts (m89-verified family):
//   a: A[row0 + (l&15)][k + (l>>4)*8 + e]
//   b: WT[col0 + (l&15)][k + (l>>4)*8 + e]   (WT[N,K] = W^T)
//   d: C[row0 + (l>>4)*4 + e][col0 + (l&15)]
__device__ __forceinline__ void mfma_gemm_core(
    const u16* __restrict__ A, int lda,
    const u16* __restrict__ WT, int ldw,
    const float* __restrict__ bias,
    float* __restrict__ Cf, u16* __restrict__ Cb, int ldc,
    int Kloop, int relu, int bx, int by)
{
    int tid = threadIdx.x;
    int lane = tid & 63, wave = tid >> 6;
    int wr = wave >> 1, wc = wave & 1;
    int row0 = by*64 + wr*32, col0 = bx*64 + wc*32;
    int r = lane & 15, kg = lane >> 4;
    const u16* Ap0 = A  + (size_t)(row0 + r)      * lda + kg*8;
    const u16* Ap1 = A  + (size_t)(row0 + 16 + r) * lda + kg*8;
    const u16* Bp0 = WT + (size_t)(col0 + r)      * ldw + kg*8;
    const u16* Bp1 = WT + (size_t)(col0 + 16 + r) * ldw + kg*8;
    f32x4 acc00 = {0.f,0.f,0.f,0.f}, acc01 = {0.f,0.f,0.f,0.f};
    f32x4 acc10 = {0.f,0.f,0.f,0.f}, acc11 = {0.f,0.f,0.f,0.f};
    for (int k = 0; k < Kloop; k += 64) {
        bf16x8 a0 = *(const bf16x8*)(Ap0 + k);
        bf16x8 a1 = *(const bf16x8*)(Ap1 + k);
        bf16x8 b0 = *(const bf16x8*)(Bp0 + k);
        bf16x8 b1 = *(const bf16x8*)(Bp1 + k);
        bf16x8 a2 = *(const bf16x8*)(Ap0 + k + 32);
        bf16x8 a3 = *(const bf16x8*)(Ap1 + k + 32);
        bf16x8 b2 = *(const bf16x8*)(Bp0 + k + 32);
        bf16x8 b3 = *(const bf16x8*)(Bp1 + k + 32);
        acc00 = __builtin_amdgcn_mfma_f32_16x16x32_bf16(a0, b0, acc00, 0, 0, 0);
        acc01 = __builtin_amdgcn_mfma_f32_16x16x32_bf16(a0, b1, acc01, 0, 0, 0);
        acc10 = __builtin_amdgcn_mfma_f32_16x16x32_bf16(a1, b0, acc10, 0, 0, 0);
        acc11 = __builtin_amdgcn_mfma_f32_16x16x32_bf16(a1, b1, acc11, 0, 0, 0);
        acc00 = __builtin_amdgcn_mfma_f32_16x16x32_bf16(a2, b2, acc00, 0, 0, 0);
        acc01 = __builtin_amdgcn_mfma_f32_16x16x32_bf16(a2, b3, acc01, 0, 0, 0);
        acc10 = __builtin_amdgcn_mfma_f32_16x16x32_bf16(a3, b2, acc10, 0, 0, 0);
        acc11 = __builtin_amdgcn_mfma_f32_16x16x32_bf16(a3, b3, acc11, 0, 0, 0);
    }
    float b0s = bias ? bias[col0 + r]      : 0.f;
    float b1s = bias ? bias[col0 + 16 + r] : 0.f;
    #pragma unroll
    for (int e = 0; e < 4; ++e) {
        int rr0 = row0 + kg*4 + e;
        int rr1 = rr0 + 16;
        float v00 = acc00[e] + b0s, v01 = acc01[e] + b1s;
        float v10 = acc10[e] + b0s, v11 = acc11[e] + b1s;
        if (relu) {
            v00 = fmaxf(v00, 0.f); v01 = fmaxf(v01, 0.f);
            v10 = fmaxf(v10, 0.f); v11 = fmaxf(v11, 0.f);
        }
        if (Cf) {
            Cf[(size_t)rr0*ldc + col0 + r]      = v00;
            Cf[(size_t)rr0*ldc + col0 + 16 + r] = v01;
            Cf[(size_t)rr1*ldc + col0 + r]      = v10;
            Cf[(size_t)rr1*ldc + col0 + 16 + r] = v11;
        }
        if (Cb) {
            Cb[(size_t)rr0*ldc + col0 + r]      = f2bf(v00);
            Cb[(size_t)rr0*ldc + col0 + 16 + r] = f2bf(v01);
            Cb[(size_t)rr1*ldc + col0 + r]      = f2bf(v10);
            Cb[(size_t)rr1*ldc + col0 + 16 + r] = f2bf(v11);
        }
    }
}

// Fused QKV projections (z selects)
struct Proj3Args {
    const u16* A[3];
    const u16* WT[3];
    const float* bias[3];
    float* C[3];
};
__global__ __launch_bounds__(256) void proj3_mfma(Proj3Args pa)
{
    int j = blockIdx.z;
    mfma_gemm_core(pa.A[j], Dsz, pa.WT[j], Dsz, pa.bias[j],
                   pa.C[j], nullptr, Dsz, Dsz, 0, blockIdx.x, blockIdx.y);
}

// Full-K GEMM, optional relu, f32 and/or bf16 output
__global__ __launch_bounds__(256) void gemm_mfma(
    const u16* __restrict__ A, int lda, const u16* __restrict__ WT, int ldw,
    const float* __restrict__ bias, float* __restrict__ Cf, u16* __restrict__ Cb,
    int ldc, int Kloop, int relu)
{
    mfma_gemm_core(A, lda, WT, ldw, bias, Cf, Cb, ldc, Kloop, relu,
                   blockIdx.x, blockIdx.y);
}

// Split-K GEMM: z = k-slice, partials to Cpart + z*pstride (f32);
// bias only on slice 0; consumer LN sums slices.
__global__ __launch_bounds__(256) void gemm_mfma_splitk(
    const u16* __restrict__ A, int lda, const u16* __restrict__ WT, int ldw,
    const float* __restrict__ bias, float* __restrict__ Cpart,
    int ldc, int Ks, size_t pstride)
{
    int s = blockIdx.z;
    mfma_gemm_core(A + (size_t)s * Ks, lda, WT + (size_t)s * Ks, ldw,
                   (s == 0) ? bias : nullptr,
                   Cpart + (size_t)s * pstride, nullptr, ldc, Ks, 0,
                   blockIdx.x, blockIdx.y);
}

// ---------------- Attention (2-slot softmax per head) ----------------
__global__ __launch_bounds__(64) void attn_kernel(
    const float* __restrict__ qh, const float* __restrict__ kh,
    const float* __restrict__ vh, u16* __restrict__ ob)
{
    int rblk = blockIdx.x;           // 0..511
    int p = rblk & (Psz - 1);
    int lane = threadIdx.x;
    const float* q  = qh + (size_t)rblk * Dsz;
    const float* k0 = kh + (size_t)(2*p) * Dsz;
    const float* k1 = k0 + Dsz;
    const float* v0 = vh + (size_t)(2*p) * Dsz;
    const float* v1 = v0 + Dsz;
    u16* o = ob + (size_t)rblk * Dsz;
    #pragma unroll
    for (int h = 0; h < Hsz; ++h) {
        int idx = h * DHsz + lane;
        float qv = q[idx];
        float s0 = qv * k0[idx];
        float s1 = qv * k1[idx];
        #pragma unroll
        for (int off = 32; off; off >>= 1) {
            s0 += __shfl_xor(s0, off);
            s1 += __shfl_xor(s1, off);
        }
        s0 *= 0.125f;   // 1/sqrt(64)
        s1 *= 0.125f;
        float m = fmaxf(s0, s1);
        float e0 = expf(s0 - m), e1 = expf(s1 - m);
        float inv = 1.f / (e0 + e1);
        o[idx] = f2bf((e0 * inv) * v0[idx] + (e1 * inv) * v1[idx]);
    }
}

// ---------------- Residual + partial-sum + LayerNorm (LN1) ----------------
__global__ __launch_bounds__(256) void ln_kernel(
    const float* __restrict__ x, const float* __restrict__ y,
    int nparts, size_t pstride,
    const float* __restrict__ g, const float* __restrict__ b,
    float* __restrict__ out, u16* __restrict__ out16)
{
    __shared__ float sb[4];
    int rr = blockIdx.x;
    int t = threadIdx.x;
    float v[3];
    float s = 0.f;
    #pragma unroll
    for (int i = 0; i < 3; ++i) {
        int d = t + i * 256;
        float acc = x[(size_t)rr*Dsz + d];
        for (int q = 0; q < nparts; ++q)
            acc += y[(size_t)q*pstride + (size_t)rr*Dsz + d];
        v[i] = acc;
        s += acc;
    }
    float mean = blk_sum(s, sb) * (1.0f / Dsz);
    float sv = 0.f;
    #pragma unroll
    for (int i = 0; i < 3; ++i) { float d0 = v[i] - mean; sv += d0 * d0; }
    float var = blk_sum(sv, sb) * (1.0f / Dsz);
    float rstd = 1.0f / sqrtf(var + EPS_LN);
    #pragma unroll
    for (int i = 0; i < 3; ++i) {
        int d = t + i * 256;
        float o = (v[i] - mean) * rstd * g[d] + b[d];
        out[(size_t)rr*Dsz + d] = o;
        if (out16) out16[(size_t)rr*Dsz + d] = f2bf(o);
    }
}

// ---------------- LN2 fused with per-row loss sumsq ----------------
// rowsq[r] = sum_d (s_emb[p][d] - LN2(h + parts)[r][d] + EPS_TRIP)^2
__global__ __launch_bounds__(256) void ln2_loss_kernel(
    const float* __restrict__ x, const float* __restrict__ y,
    int nparts, size_t pstride,
    const float* __restrict__ g, const float* __restrict__ b,
    const float* __restrict__ mem, float* __restrict__ rowsq)
{
    __shared__ float sb[4];
    int rr = blockIdx.x;
    int p = rr & (Psz - 1);
    const float* se = mem + (size_t)(2*p+1) * Dsz;
    int t = threadIdx.x;
    float v[3];
    float s = 0.f;
    #pragma unroll
    for (int i = 0; i < 3; ++i) {
        int d = t + i * 256;
        float acc = x[(size_t)rr*Dsz + d];
        for (int q = 0; q < nparts; ++q)
            acc += y[(size_t)q*pstride + (size_t)rr*Dsz + d];
        v[i] = acc;
        s += acc;
    }
    float mean = blk_sum(s, sb) * (1.0f / Dsz);
    float sv = 0.f;
    #pragma unroll
    for (int i = 0; i < 3; ++i) { float d0 = v[i] - mean; sv += d0 * d0; }
    float var = blk_sum(sv, sb) * (1.0f / Dsz);
    float rstd = 1.0f / sqrtf(var + EPS_LN);
    float dsq = 0.f;
    #pragma unroll
    for (int i = 0; i < 3; ++i) {
        int d = t + i * 256;
        float o = (v[i] - mean) * rstd * g[d] + b[d];
        float diff = se[d] - o + EPS_TRIP;
        dsq += diff * diff;
    }
    float tot = blk_sum(dsq, sb);
    if (t == 0) rowsq[rr] = tot;
}

// ---------------- Final triplet loss (1 block, plain store) ----------------
__global__ __launch_bounds__(256) void loss_final_kernel(
    const float* __restrict__ rowsq, float* __restrict__ d_out)
{
    __shared__ float sb[4];
    int t = threadIdx.x;
    float dp = sqrtf(rowsq[t]);
    float dn = sqrtf(rowsq[Psz + t]);
    float l = fmaxf(dp - dn + 1.0f, 0.f);
    float tot = blk_sum(l, sb);
    if (t == 0) d_out[0] = tot * (1.0f / Psz);
}

// ---------------- Launch ----------------
extern "C" void kernel_launch(void* const* d_in, const int* in_sizes, int n_in,
                              void* d_out, int out_size, void* d_ws, size_t ws_size,
                              hipStream_t stream) {
    const float* sent  = (const float*)d_in[0];
    const int*   sidx  = (const int*)d_in[1];
    const int*   sspan = (const int*)d_in[2];
    const int*   pspan = (const int*)d_in[3];
    const int*   nspan = (const int*)d_in[4];
    const float* Wq = (const float*)d_in[5];
    const float* bq = (const float*)d_in[6];
    const float* Wk = (const float*)d_in[7];
    const float* bk = (const float*)d_in[8];
    const float* Wv = (const float*)d_in[9];
    const float* bv = (const float*)d_in[10];
    const float* Wo = (const float*)d_in[11];
    const float* bo = (const float*)d_in[12];
    const float* ln1g = (const float*)d_in[13];
    const float* ln1b = (const float*)d_in[14];
    const float* ln2g = (const float*)d_in[15];
    const float* ln2b = (const float*)d_in[16];
    const float* W1 = (const float*)d_in[17];
    const float* b1 = (const float*)d_in[18];
    const float* W2 = (const float*)d_in[19];
    const float* b2 = (const float*)d_in[20];
    float* out = (float*)d_out;

    // Workspace (floats); F = 512*768 = 393216 (1.5 MB). ws_size ~268 MB;
    // plain non-aliased layout, total 25F ~= 39 MB.
    const size_t F = (size_t)Msz * Dsz;
    float* ws    = (float*)d_ws;
    float* mem   = ws + 0*F;
    float* qin   = ws + 1*F;
    float* hbuf  = ws + 2*F;
    float* partb = ws + 3*F;     // 4 split-K partials (3F..7F)
    float* qh    = ws + 7*F;
    float* kh    = ws + 8*F;
    float* vh    = ws + 9*F;
    float* rowsq = ws + 10*F;    // 512 floats
    u16* memb    = (u16*)(ws + 11*F);          // [512,768] bf16
    u16* qinb    = memb + F;                   // [512,768] bf16 (ends at 12F)
    u16* obufb   = (u16*)(ws + 12*F);          // [512,768] bf16
    u16* hbufb   = obufb + F;                  // [512,768] bf16 (ends at 13F)
    u16* f1b     = (u16*)(ws + 13*F);          // [512,3072] bf16 = 2F floats
    u16* WqT     = (u16*)(ws + 15*F);          // [768,768]  bf16
    u16* WkT     = (u16*)(ws + 16*F);
    u16* WvT     = (u16*)(ws + 17*F);
    u16* WoT     = (u16*)(ws + 18*F);
    u16* W1T     = (u16*)(ws + 19*F);          // [3072,768] bf16 = 3F floats
    u16* W2T     = (u16*)(ws + 22*F);          // [768,3072] bf16 = 3F floats -> 25F

    // 1. pool (256 blocks) + weight cvt (1728 blocks) in one launch
    PoolCvtArgs pc;
    pc.sent = sent; pc.sidx = sidx; pc.sspan = sspan; pc.pspan = pspan; pc.nspan = nspan;
    pc.mem = mem; pc.qin = qin; pc.memb = memb; pc.qinb = qinb;
    pc.csrc[0]=Wq; pc.csrc[1]=Wk; pc.csrc[2]=Wv; pc.csrc[3]=Wo; pc.csrc[4]=W1; pc.csrc[5]=W2;
    pc.cdst[0]=WqT; pc.cdst[1]=WkT; pc.cdst[2]=WvT; pc.cdst[3]=WoT; pc.cdst[4]=W1T; pc.cdst[5]=W2T;
    pc.cK[0]=Dsz; pc.cK[1]=Dsz; pc.cK[2]=Dsz; pc.cK[3]=Dsz; pc.cK[4]=Dsz;  pc.cK[5]=DFFsz;
    pc.cN[0]=Dsz; pc.cN[1]=Dsz; pc.cN[2]=Dsz; pc.cN[3]=Dsz; pc.cN[4]=DFFsz; pc.cN[5]=Dsz;
    int acc_t = 0;
    for (int i = 0; i < 6; ++i) {
        pc.ct0[i] = acc_t;
        acc_t += (pc.cK[i] >> 6) * (pc.cN[i] >> 6);
    }
    pc.ct0[6] = acc_t;   // 1728
    pool_cvt_kernel<<<Psz + acc_t, 256, 0, stream>>>(pc);

    // 2. fused K/V/Q projections (12x8x3 = 288 blocks)
    Proj3Args pa;
    pa.A[0]=memb; pa.WT[0]=WkT; pa.bias[0]=bk; pa.C[0]=kh;
    pa.A[1]=memb; pa.WT[1]=WvT; pa.bias[1]=bv; pa.C[1]=vh;
    pa.A[2]=qinb; pa.WT[2]=WqT; pa.bias[2]=bq; pa.C[2]=qh;
    proj3_mfma<<<dim3(Dsz/64, Msz/64, 3), 256, 0, stream>>>(pa);

    // 3. attention -> bf16 (512 one-wave blocks)
    attn_kernel<<<Msz, 64, 0, stream>>>(qh, kh, vh, obufb);

    // 4. Wo projection split-K=4 (Ks=192; 384 blocks)
    gemm_mfma_splitk<<<dim3(Dsz/64, Msz/64, 4), 256, 0, stream>>>(
        obufb, Dsz, WoT, Dsz, bo, partb, Dsz, Dsz/4, F);

    // 5. h = LN1(qin + sum partials), f32+bf16 (512 blocks)
    ln_kernel<<<Msz, 256, 0, stream>>>(qin, partb, 4, F, ln1g, ln1b, hbuf, hbufb);

    // 6. f1 = relu(h @ W1 + b1) -> bf16 (48x8 = 384 blocks)
    gemm_mfma<<<dim3(DFFsz/64, Msz/64), 256, 0, stream>>>(
        hbufb, Dsz, W1T, Dsz, b1, nullptr, f1b, DFFsz, Dsz, 1);

    // 7. f2 partials = f1 @ W2 + b2, split-K=4 (Ks=768; 384 blocks)
    gemm_mfma_splitk<<<dim3(Dsz/64, Msz/64, 4), 256, 0, stream>>>(
        f1b, DFFsz, W2T, DFFsz, b2, partb, Dsz, DFFsz/4, F);

    // 8. LN2 + per-row loss sumsq (512 blocks), then final reduce (1 block)
    ln2_loss_kernel<<<Msz, 256, 0, stream>>>(hbuf, partb, 4, F, ln2g, ln2b, mem, rowsq);
    loss_final_kernel<<<1, 256, 0, stream>>>(rowsq, out);
}